// Round 2
// baseline (47135.669 us; speedup 1.0000x reference)
//
#include <hip/hip_runtime.h>
#include <math.h>

#define SS 512
#define BB 64
#define EE 256
#define HH 512
#define NT 9
#define NWG 256

// ws layout (float32 elements):
//  hs   : (SS+1)*BB*HH  at 0            (slot 0 = h_{-1} = zeros)
//  em   : SS*BB*NT      at EM_OFF
//  num  : 64            at NUM_OFF
//  norm : 64            at NORM_OFF
//  bar  : 2*(SS+1) u32  at BAR_OFF (cnt[513], flag[513])
#define HS_ELEMS ((size_t)(SS + 1) * BB * HH)
#define EM_OFF   HS_ELEMS
#define NUM_OFF  (EM_OFF + (size_t)SS * BB * NT)
#define NORM_OFF (NUM_OFF + 64)
#define BAR_OFF  (NORM_OFF + 64)

__global__ __launch_bounds__(256) void init_barriers(float* __restrict__ ws) {
    unsigned* bar = (unsigned*)(ws + BAR_OFF);
    int idx = blockIdx.x * 256 + threadIdx.x;
    if (idx < 2 * (SS + 1)) bar[idx] = 0u;
}

// Persistent LSTM: 256 WGs x 512 threads, one step per grid-barrier round.
// WG (slice = wg&31, bg = wg>>5): units slice*16..+16, batches bg*8..+8.
// Wave w: local gate-rows w*8..w*8+7 (row l = gate*16 + unit_local).
// Lane L: b_l = L&7, kc = L>>3.
__global__ __launch_bounds__(512) void lstm_persistent(
    const float* __restrict__ Whh, const float* __restrict__ Wih,
    const float* __restrict__ bih, const float* __restrict__ bhh,
    const float* __restrict__ emb, const int* __restrict__ x,
    float* __restrict__ ws)
{
    const int wg    = blockIdx.x;
    const int slice = wg & 31;
    const int bg    = wg >> 5;
    const int tid   = threadIdx.x;
    const int w     = tid >> 6;
    const int L     = tid & 63;
    const int b_l   = L & 7;
    const int kc    = L >> 3;
    const int b     = bg * 8 + b_l;

    float* hs = ws;
    unsigned* cnt  = (unsigned*)(ws + BAR_OFF);
    unsigned* flag = cnt + (SS + 1);

    __shared__ float h_l[8 * 520];     // [b_l][k], stride 520 (16B-aligned rows)
    __shared__ float gsm[64][8];
    __shared__ float cs_l[16][8];      // c-state [unit_local][b_l]

    int grow[8];
#pragma unroll
    for (int r = 0; r < 8; r++) {
        int l = w * 8 + r;
        grow[r] = (l >> 4) * HH + slice * 16 + (l & 15);
    }

    // ---- init: h0 = 0 (agent-scope), c = 0 ----
    if (tid < 128) {
        const int u  = tid & 15;
        const int bb = tid >> 4;
        const int gu = slice * 16 + u;
        const int gb = bg * 8 + bb;
        cs_l[u][bb] = 0.0f;
        __hip_atomic_store(&hs[(size_t)gb * HH + gu], 0.0f,
                           __ATOMIC_RELAXED, __HIP_MEMORY_SCOPE_AGENT);
    }
    __syncthreads();   // drain stores before arrive
    if (tid == 0) {
        unsigned old = __hip_atomic_fetch_add(&cnt[0], 1u, __ATOMIC_ACQ_REL,
                                              __HIP_MEMORY_SCOPE_AGENT);
        if (old == NWG - 1)
            __hip_atomic_store(&flag[0], 1u, __ATOMIC_RELEASE,
                               __HIP_MEMORY_SCOPE_AGENT);
    }

    // ---- ih-gates for t=0 (no h dependence) ----
    float acc_ih[8];
    {
        const int xv = x[0 * BB + b];
        const float* erow = emb + (size_t)xv * EE;
#pragma unroll
        for (int r = 0; r < 8; r++) acc_ih[r] = 0.0f;
        for (int c = 0; c < 8; c++) {
            const int k0 = c * 32 + kc * 4;
            float4 e4 = *(const float4*)(erow + k0);
            e4.x *= 16.0f; e4.y *= 16.0f; e4.z *= 16.0f; e4.w *= 16.0f;
#pragma unroll
            for (int r = 0; r < 8; r++) {
                float4 w4 = *(const float4*)(Wih + (size_t)grow[r] * EE + k0);
                acc_ih[r] += w4.x * e4.x + w4.y * e4.y + w4.z * e4.z + w4.w * e4.w;
            }
        }
    }
    if (tid == 0) {
        while (__hip_atomic_load(&flag[0], __ATOMIC_ACQUIRE,
                                 __HIP_MEMORY_SCOPE_AGENT) == 0u) {}
    }
    __syncthreads();

    for (int t = 0; t < SS; t++) {
        // ---- stage h_t (our 8 batches, all 512 k) into LDS ----
        const float* hsrc = hs + (size_t)t * BB * HH + (size_t)bg * 8 * HH;
#pragma unroll
        for (int j = 0; j < 8; j++) {
            int idx = j * 512 + tid;
            float v = __hip_atomic_load(&hsrc[idx], __ATOMIC_RELAXED,
                                        __HIP_MEMORY_SCOPE_AGENT);
            h_l[(idx >> 9) * 520 + (idx & 511)] = v;
        }
        __syncthreads();

        // ---- hh gates ----
        float acc[8];
#pragma unroll
        for (int r = 0; r < 8; r++) acc[r] = acc_ih[r];
        const float* hrow = h_l + b_l * 520;
        for (int c = 0; c < 16; c++) {
            const int k0 = c * 32 + kc * 4;
            float4 h4 = *(const float4*)(hrow + k0);
#pragma unroll
            for (int r = 0; r < 8; r++) {
                float4 w4 = *(const float4*)(Whh + (size_t)grow[r] * HH + k0);
                acc[r] += w4.x * h4.x + w4.y * h4.y + w4.z * h4.z + w4.w * h4.w;
            }
        }

        // reduce over 8 kc-lanes
#pragma unroll
        for (int r = 0; r < 8; r++) {
            acc[r] += __shfl_xor(acc[r], 8, 64);
            acc[r] += __shfl_xor(acc[r], 16, 64);
            acc[r] += __shfl_xor(acc[r], 32, 64);
        }
        float myv = acc[0];
#pragma unroll
        for (int r = 1; r < 8; r++) if (kc == r) myv = acc[r];
        gsm[w * 8 + kc][b_l] = myv;
        __syncthreads();

        // ---- activations + state update + h store ----
        if (tid < 128) {
            const int u  = tid & 15;
            const int bb = tid >> 4;
            const int gu = slice * 16 + u;
            float gi = gsm[0 * 16 + u][bb] + bih[0 * HH + gu] + bhh[0 * HH + gu];
            float gf = gsm[1 * 16 + u][bb] + bih[1 * HH + gu] + bhh[1 * HH + gu];
            float gg = gsm[2 * 16 + u][bb] + bih[2 * HH + gu] + bhh[2 * HH + gu];
            float go = gsm[3 * 16 + u][bb] + bih[3 * HH + gu] + bhh[3 * HH + gu];
            float i_ = 1.0f / (1.0f + expf(-gi));
            float f_ = 1.0f / (1.0f + expf(-gf));
            float o_ = 1.0f / (1.0f + expf(-go));
            const int gb = bg * 8 + bb;
            float cn = f_ * cs_l[u][bb] + i_ * tanhf(gg);
            float hn = o_ * tanhf(cn);
            cs_l[u][bb] = cn;
            __hip_atomic_store(&hs[(size_t)(t + 1) * BB * HH + (size_t)gb * HH + gu],
                               hn, __ATOMIC_RELAXED, __HIP_MEMORY_SCOPE_AGENT);
        }
        __syncthreads();   // drains vmcnt: h stores globally visible (LLC)

        // ---- grid barrier t+1, with ih(t+1) overlapped in the wait window ----
        if (tid == 0) {
            unsigned old = __hip_atomic_fetch_add(&cnt[t + 1], 1u, __ATOMIC_ACQ_REL,
                                                  __HIP_MEMORY_SCOPE_AGENT);
            if (old == NWG - 1)
                __hip_atomic_store(&flag[t + 1], 1u, __ATOMIC_RELEASE,
                                   __HIP_MEMORY_SCOPE_AGENT);
        }
        if (t + 1 < SS) {
            const int xv = x[(t + 1) * BB + b];
            const float* erow = emb + (size_t)xv * EE;
#pragma unroll
            for (int r = 0; r < 8; r++) acc_ih[r] = 0.0f;
            for (int c = 0; c < 8; c++) {
                const int k0 = c * 32 + kc * 4;
                float4 e4 = *(const float4*)(erow + k0);
                e4.x *= 16.0f; e4.y *= 16.0f; e4.z *= 16.0f; e4.w *= 16.0f;
#pragma unroll
                for (int r = 0; r < 8; r++) {
                    float4 w4 = *(const float4*)(Wih + (size_t)grow[r] * EE + k0);
                    acc_ih[r] += w4.x * e4.x + w4.y * e4.y + w4.z * e4.z + w4.w * e4.w;
                }
            }
        }
        if (tid == 0) {
            while (__hip_atomic_load(&flag[t + 1], __ATOMIC_ACQUIRE,
                                     __HIP_MEMORY_SCOPE_AGENT) == 0u) {}
        }
        __syncthreads();
    }
}

// one wave per (t,b): logits = h @ W_out^T + b_out, then log_softmax
__global__ __launch_bounds__(256) void emis_kernel(
    const float* __restrict__ Wout, const float* __restrict__ bout,
    float* __restrict__ ws)
{
    int wid = blockIdx.x * 4 + (threadIdx.x >> 6);
    int L   = threadIdx.x & 63;
    int t = wid >> 6;
    int b = wid & 63;
    const float* h = ws + (size_t)(t + 1) * BB * HH + (size_t)b * HH;
    float hv[8];
#pragma unroll
    for (int i = 0; i < 8; i++) hv[i] = h[i * 64 + L];
    float acc[9];
#pragma unroll
    for (int tg = 0; tg < 9; tg++) acc[tg] = 0.0f;
    for (int i = 0; i < 8; i++) {
#pragma unroll
        for (int tg = 0; tg < 9; tg++)
            acc[tg] += Wout[tg * HH + i * 64 + L] * hv[i];
    }
#pragma unroll
    for (int tg = 0; tg < 9; tg++) {
        acc[tg] += __shfl_xor(acc[tg], 1, 64);
        acc[tg] += __shfl_xor(acc[tg], 2, 64);
        acc[tg] += __shfl_xor(acc[tg], 4, 64);
        acc[tg] += __shfl_xor(acc[tg], 8, 64);
        acc[tg] += __shfl_xor(acc[tg], 16, 64);
        acc[tg] += __shfl_xor(acc[tg], 32, 64);
    }
    float lg[9];
#pragma unroll
    for (int tg = 0; tg < 9; tg++) lg[tg] = acc[tg] + bout[tg];
    float m = lg[0];
#pragma unroll
    for (int tg = 1; tg < 9; tg++) m = fmaxf(m, lg[tg]);
    float ssum = 0.0f;
#pragma unroll
    for (int tg = 0; tg < 9; tg++) ssum += expf(lg[tg] - m);
    float lse = m + logf(ssum);
    float myo = lg[0] - lse;
#pragma unroll
    for (int tg = 1; tg < 9; tg++) if (L == tg) myo = lg[tg] - lse;
    if (L < 9) ws[EM_OFF + (size_t)wid * 9 + L] = myo;
}

// CRF numerator, wave per b, lanes split s (no recurrence in the sum)
__global__ __launch_bounds__(512) void crf_num(
    const int* __restrict__ x, const int* __restrict__ bio,
    const float* __restrict__ start_t, const float* __restrict__ end_t,
    const float* __restrict__ trans, float* __restrict__ ws)
{
    int b = blockIdx.x * 8 + (threadIdx.x >> 6);
    int L = threadIdx.x & 63;
    const float* em = ws + EM_OFF;
    float sum = 0.0f;
    int cnt = 0;
#pragma unroll
    for (int j = 0; j < 8; j++) {
        int s = j * 64 + L;
        int tg = bio[s * BB + b];
        bool mk = (x[s * BB + b] != 0);
        cnt += mk ? 1 : 0;
        if (s == 0) {
            sum += start_t[tg] + em[(size_t)b * 9 + tg];
        } else if (mk) {
            int tp = bio[(s - 1) * BB + b];
            sum += em[((size_t)s * BB + b) * 9 + tg] + trans[tp * 9 + tg];
        }
    }
#pragma unroll
    for (int d = 1; d < 64; d <<= 1) {
        sum += __shfl_xor(sum, d, 64);
        cnt += __shfl_xor(cnt, d, 64);
    }
    if (L == 0) {
        int se = cnt - 1;
        sum += end_t[bio[se * BB + b]];
        ws[NUM_OFF + b] = sum;
    }
}

// CRF forward (log-partition). 8 WGs x 128 thr: thread = (j = tid>>3, b_l = tid&7)
__global__ __launch_bounds__(128) void crf_fwd(
    const int* __restrict__ x,
    const float* __restrict__ start_t, const float* __restrict__ end_t,
    const float* __restrict__ trans, float* __restrict__ ws)
{
    const float* em = ws + EM_OFF;
    int b_l = threadIdx.x & 7;
    int j   = threadIdx.x >> 3;
    int b   = blockIdx.x * 8 + b_l;
    __shared__ float sc[9][8];
    float tc[9];
    if (j < 9) {
#pragma unroll
        for (int i = 0; i < 9; i++) tc[i] = trans[i * 9 + j];
        sc[j][b_l] = start_t[j] + em[(size_t)b * 9 + j];
    }
    __syncthreads();
    for (int s = 1; s < SS; s++) {
        float nv = 0.0f;
        if (j < 9) {
            float sv[9];
            float m = -3.4e38f;
#pragma unroll
            for (int i = 0; i < 9; i++) {
                sv[i] = sc[i][b_l] + tc[i];
                m = fmaxf(m, sv[i]);
            }
            float ssum = 0.0f;
#pragma unroll
            for (int i = 0; i < 9; i++) ssum += expf(sv[i] - m);
            nv = m + logf(ssum) + em[((size_t)s * BB + b) * 9 + j];
        }
        bool mk = (x[s * BB + b] != 0);
        __syncthreads();
        if (j < 9 && mk) sc[j][b_l] = nv;
        __syncthreads();
    }
    if (j == 0) {
        float m = -3.4e38f;
#pragma unroll
        for (int i = 0; i < 9; i++) m = fmaxf(m, sc[i][b_l] + end_t[i]);
        float ssum = 0.0f;
#pragma unroll
        for (int i = 0; i < 9; i++) ssum += expf(sc[i][b_l] + end_t[i] - m);
        ws[NORM_OFF + b] = m + logf(ssum);
    }
}

// Viterbi: forward max-product with in-LDS history + backtrace. 8 WGs x 128 thr.
__global__ __launch_bounds__(128) void viterbi_kernel(
    const float* __restrict__ start_t, const float* __restrict__ end_t,
    const float* __restrict__ trans, const float* __restrict__ ws,
    float* __restrict__ out)
{
    const float* em = ws + EM_OFF;
    int b_l = threadIdx.x & 7;
    int j   = threadIdx.x >> 3;
    int b   = blockIdx.x * 8 + b_l;
    __shared__ float sc[9][8];
    __shared__ unsigned char hist[SS - 1][8][9];
    float tc[9];
    if (j < 9) {
#pragma unroll
        for (int i = 0; i < 9; i++) tc[i] = trans[i * 9 + j];
        sc[j][b_l] = start_t[j] + em[(size_t)b * 9 + j];
    }
    __syncthreads();
    for (int s = 1; s < SS; s++) {
        float nv = 0.0f;
        if (j < 9) {
            float best = sc[0][b_l] + tc[0];
            int bi = 0;
#pragma unroll
            for (int i = 1; i < 9; i++) {
                float v = sc[i][b_l] + tc[i];
                if (v > best) { best = v; bi = i; }
            }
            hist[s - 1][b_l][j] = (unsigned char)bi;
            nv = best + em[((size_t)s * BB + b) * 9 + j];
        }
        __syncthreads();
        if (j < 9) sc[j][b_l] = nv;
        __syncthreads();
    }
    if (threadIdx.x < 8) {
        int bl = threadIdx.x;
        int gb = blockIdx.x * 8 + bl;
        float best = sc[0][bl] + end_t[0];
        int cur = 0;
#pragma unroll
        for (int i = 1; i < 9; i++) {
            float v = sc[i][bl] + end_t[i];
            if (v > best) { best = v; cur = i; }
        }
        out[1 + (size_t)(SS - 1) * BB + gb] = (float)cur;
        for (int s = SS - 2; s >= 0; s--) {
            cur = hist[s][bl][cur];
            out[1 + (size_t)s * BB + gb] = (float)cur;
        }
    }
}

__global__ __launch_bounds__(64) void final_llh(const float* __restrict__ ws,
                                               float* __restrict__ out)
{
    int L = threadIdx.x;
    float v = ws[NUM_OFF + L] - ws[NORM_OFF + L];
    v += __shfl_xor(v, 1, 64);
    v += __shfl_xor(v, 2, 64);
    v += __shfl_xor(v, 4, 64);
    v += __shfl_xor(v, 8, 64);
    v += __shfl_xor(v, 16, 64);
    v += __shfl_xor(v, 32, 64);
    if (L == 0) out[0] = -v;
}

extern "C" void kernel_launch(void* const* d_in, const int* in_sizes, int n_in,
                              void* d_out, int out_size, void* d_ws, size_t ws_size,
                              hipStream_t stream) {
    const int*   x       = (const int*)d_in[0];
    const int*   bio     = (const int*)d_in[1];
    const float* emb     = (const float*)d_in[2];
    const float* W_ih    = (const float*)d_in[3];
    const float* W_hh    = (const float*)d_in[4];
    const float* b_ih    = (const float*)d_in[5];
    const float* b_hh    = (const float*)d_in[6];
    const float* W_out   = (const float*)d_in[7];
    const float* b_out   = (const float*)d_in[8];
    const float* start_t = (const float*)d_in[9];
    const float* end_t   = (const float*)d_in[10];
    const float* trans   = (const float*)d_in[11];
    float* out = (float*)d_out;
    float* ws  = (float*)d_ws;

    init_barriers<<<5, 256, 0, stream>>>(ws);
    lstm_persistent<<<NWG, 512, 0, stream>>>(W_hh, W_ih, b_ih, b_hh, emb, x, ws);
    emis_kernel<<<SS * BB / 4, 256, 0, stream>>>(W_out, b_out, ws);
    crf_num<<<8, 512, 0, stream>>>(x, bio, start_t, end_t, trans, ws);
    crf_fwd<<<8, 128, 0, stream>>>(x, start_t, end_t, trans, ws);
    viterbi_kernel<<<8, 128, 0, stream>>>(start_t, end_t, trans, ws, out);
    final_llh<<<1, 64, 0, stream>>>(ws, out);
}

// Round 3
// 37773.782 us; speedup vs baseline: 1.2478x; 1.2478x over previous
//
#include <hip/hip_runtime.h>
#include <math.h>

#define SS 512
#define BB 64
#define EE 256
#define HH 512
#define NT 9
#define NWG 256
#define GBG 32   // workgroups per batch-group barrier

// ws layout (float32 elements):
//  hs   : SS*BB*HH at 0        (hs[t] = h_t)
//  em   : SS*BB*NT at EM_OFF
//  num  : 64 at NUM_OFF
//  norm : 64 at NORM_OFF
//  cnt  : SS*8*16 u32 at BAR_OFF          (64B-strided counters [t][bg])
//  flag : SS*8*16 u32 after cnt
#define HS_ELEMS ((size_t)SS * BB * HH)
#define EM_OFF   HS_ELEMS
#define NUM_OFF  (EM_OFF + (size_t)SS * BB * NT)
#define NORM_OFF (NUM_OFF + 64)
#define BAR_OFF  (NORM_OFF + 64)
#define BAR_U32S ((size_t)SS * 8 * 16)

__global__ __launch_bounds__(256) void init_barriers(float* __restrict__ ws) {
    unsigned* bar = (unsigned*)(ws + BAR_OFF);
    size_t idx = (size_t)blockIdx.x * 256 + threadIdx.x;
    if (idx < 2 * BAR_U32S) bar[idx] = 0u;
}

// Persistent LSTM: 256 WGs x 512 threads, one step per (per-bg) barrier round.
// WG (slice = wg&31, bg = wg>>5): units slice*16..+16, batches bg*8..+8.
// Wave w: local gate-rows w*8..w*8+7 (row l = gate*16 + unit_local).
// Lane L: b_l = L&7, kc = L>>3.
// ALL cross-WG data goes through RELAXED agent atomics (sc0 sc1: LLC-coherent,
// no buffer_inv -> weights stay L2-resident).
__global__ __launch_bounds__(512) void lstm_persistent(
    const float* __restrict__ Whh, const float* __restrict__ Wih,
    const float* __restrict__ bih, const float* __restrict__ bhh,
    const float* __restrict__ emb, const int* __restrict__ x,
    float* __restrict__ ws)
{
    const int wg    = blockIdx.x;
    const int slice = wg & 31;
    const int bg    = wg >> 5;
    const int tid   = threadIdx.x;
    const int w     = tid >> 6;
    const int L     = tid & 63;
    const int b_l   = L & 7;
    const int kc    = L >> 3;
    const int b     = bg * 8 + b_l;

    float* hs = ws;
    unsigned* cnt  = (unsigned*)(ws + BAR_OFF);
    unsigned* flag = cnt + BAR_U32S;

    __shared__ float h_l[8 * 520];     // [b_l][k], stride 520
    __shared__ float gsm[64][9];       // padded: no 4-way read conflict
    __shared__ float cs_l[16][8];      // c-state [unit_local][b_l]

    int grow[8];
#pragma unroll
    for (int r = 0; r < 8; r++) {
        int l = w * 8 + r;
        grow[r] = (l >> 4) * HH + slice * 16 + (l & 15);
    }

    // bias preload (activation threads only)
    float bs0 = 0.f, bs1 = 0.f, bs2 = 0.f, bs3 = 0.f;
    if (tid < 128) {
        const int u  = tid & 15;
        const int bb = tid >> 4;
        const int gu = slice * 16 + u;
        bs0 = bih[0 * HH + gu] + bhh[0 * HH + gu];
        bs1 = bih[1 * HH + gu] + bhh[1 * HH + gu];
        bs2 = bih[2 * HH + gu] + bhh[2 * HH + gu];
        bs3 = bih[3 * HH + gu] + bhh[3 * HH + gu];
        cs_l[u][bb] = 0.0f;
    }

    // h_{-1} = 0 locally (no global round-trip)
#pragma unroll
    for (int j = 0; j < 8; j++) {
        int idx = j * 512 + tid;
        h_l[(idx >> 9) * 520 + (idx & 511)] = 0.0f;
    }

    // ih-gates for t=0
    float acc_ih[8];
    {
        const int xv = x[0 * BB + b];
        const float* erow = emb + (size_t)xv * EE;
#pragma unroll
        for (int r = 0; r < 8; r++) acc_ih[r] = 0.0f;
        for (int c = 0; c < 8; c++) {
            const int k0 = c * 32 + kc * 4;
            float4 e4 = *(const float4*)(erow + k0);
            e4.x *= 16.0f; e4.y *= 16.0f; e4.z *= 16.0f; e4.w *= 16.0f;
#pragma unroll
            for (int r = 0; r < 8; r++) {
                float4 w4 = *(const float4*)(Wih + (size_t)grow[r] * EE + k0);
                acc_ih[r] += w4.x * e4.x + w4.y * e4.y + w4.z * e4.z + w4.w * e4.w;
            }
        }
    }
    __syncthreads();

    for (int t = 0; t < SS; t++) {
        // ---- hh gates ----
        float acc[8];
#pragma unroll
        for (int r = 0; r < 8; r++) acc[r] = acc_ih[r];
        const float* hrow = h_l + b_l * 520;
        for (int c = 0; c < 16; c++) {
            const int k0 = c * 32 + kc * 4;
            float4 h4 = *(const float4*)(hrow + k0);
#pragma unroll
            for (int r = 0; r < 8; r++) {
                float4 w4 = *(const float4*)(Whh + (size_t)grow[r] * HH + k0);
                acc[r] += w4.x * h4.x + w4.y * h4.y + w4.z * h4.z + w4.w * h4.w;
            }
        }

        // reduce over 8 kc-lanes
#pragma unroll
        for (int r = 0; r < 8; r++) {
            acc[r] += __shfl_xor(acc[r], 8, 64);
            acc[r] += __shfl_xor(acc[r], 16, 64);
            acc[r] += __shfl_xor(acc[r], 32, 64);
        }
        float myv = acc[0];
#pragma unroll
        for (int r = 1; r < 8; r++) if (kc == r) myv = acc[r];
        gsm[w * 8 + kc][b_l] = myv;
        __syncthreads();

        // ---- activations + state update + h_t store (relaxed agent) ----
        if (tid < 128) {
            const int u  = tid & 15;
            const int bb = tid >> 4;
            const int gu = slice * 16 + u;
            float gi = gsm[0 * 16 + u][bb] + bs0;
            float gf = gsm[1 * 16 + u][bb] + bs1;
            float gg = gsm[2 * 16 + u][bb] + bs2;
            float go = gsm[3 * 16 + u][bb] + bs3;
            float i_ = 1.0f / (1.0f + expf(-gi));
            float f_ = 1.0f / (1.0f + expf(-gf));
            float o_ = 1.0f / (1.0f + expf(-go));
            const int gb = bg * 8 + bb;
            float cn = f_ * cs_l[u][bb] + i_ * tanhf(gg);
            float hn = o_ * tanhf(cn);
            cs_l[u][bb] = cn;
            __hip_atomic_store(&hs[(size_t)t * BB * HH + (size_t)gb * HH + gu],
                               hn, __ATOMIC_RELAXED, __HIP_MEMORY_SCOPE_AGENT);
        }
        __syncthreads();   // s_waitcnt vmcnt(0) before s_barrier: h stores at LLC

        // ---- arrive at per-bg barrier t ----
        if (tid == 0) {
            unsigned old = __hip_atomic_fetch_add(&cnt[((size_t)t * 8 + bg) * 16], 1u,
                                                  __ATOMIC_RELAXED,
                                                  __HIP_MEMORY_SCOPE_AGENT);
            if (old == GBG - 1)
                __hip_atomic_store(&flag[((size_t)t * 8 + bg) * 16], 1u,
                                   __ATOMIC_RELAXED, __HIP_MEMORY_SCOPE_AGENT);
        }

        if (t + 1 < SS) {
            // ---- ih(t+1) overlapped with the wait window ----
            {
                const int xv = x[(t + 1) * BB + b];
                const float* erow = emb + (size_t)xv * EE;
#pragma unroll
                for (int r = 0; r < 8; r++) acc_ih[r] = 0.0f;
                for (int c = 0; c < 8; c++) {
                    const int k0 = c * 32 + kc * 4;
                    float4 e4 = *(const float4*)(erow + k0);
                    e4.x *= 16.0f; e4.y *= 16.0f; e4.z *= 16.0f; e4.w *= 16.0f;
#pragma unroll
                    for (int r = 0; r < 8; r++) {
                        float4 w4 = *(const float4*)(Wih + (size_t)grow[r] * EE + k0);
                        acc_ih[r] += w4.x * e4.x + w4.y * e4.y + w4.z * e4.z + w4.w * e4.w;
                    }
                }
            }
            if (tid == 0) {
                while (__hip_atomic_load(&flag[((size_t)t * 8 + bg) * 16],
                                         __ATOMIC_RELAXED,
                                         __HIP_MEMORY_SCOPE_AGENT) == 0u) {}
            }
            __syncthreads();

            // ---- stage h_t into LDS (relaxed agent loads from LLC) ----
            const float* hsrc = hs + (size_t)t * BB * HH + (size_t)bg * 8 * HH;
#pragma unroll
            for (int j = 0; j < 8; j++) {
                int idx = j * 512 + tid;
                float v = __hip_atomic_load(&hsrc[idx], __ATOMIC_RELAXED,
                                            __HIP_MEMORY_SCOPE_AGENT);
                h_l[(idx >> 9) * 520 + (idx & 511)] = v;
            }
            __syncthreads();
        }
    }
}

// one wave per (t,b): logits = h @ W_out^T + b_out, then log_softmax
__global__ __launch_bounds__(256) void emis_kernel(
    const float* __restrict__ Wout, const float* __restrict__ bout,
    float* __restrict__ ws)
{
    int wid = blockIdx.x * 4 + (threadIdx.x >> 6);  // t*64 + b
    int L   = threadIdx.x & 63;
    const float* h = ws + (size_t)wid * HH;
    float hv[8];
#pragma unroll
    for (int i = 0; i < 8; i++) hv[i] = h[i * 64 + L];
    float acc[9];
#pragma unroll
    for (int tg = 0; tg < 9; tg++) acc[tg] = 0.0f;
    for (int i = 0; i < 8; i++) {
#pragma unroll
        for (int tg = 0; tg < 9; tg++)
            acc[tg] += Wout[tg * HH + i * 64 + L] * hv[i];
    }
#pragma unroll
    for (int tg = 0; tg < 9; tg++) {
        acc[tg] += __shfl_xor(acc[tg], 1, 64);
        acc[tg] += __shfl_xor(acc[tg], 2, 64);
        acc[tg] += __shfl_xor(acc[tg], 4, 64);
        acc[tg] += __shfl_xor(acc[tg], 8, 64);
        acc[tg] += __shfl_xor(acc[tg], 16, 64);
        acc[tg] += __shfl_xor(acc[tg], 32, 64);
    }
    float lg[9];
#pragma unroll
    for (int tg = 0; tg < 9; tg++) lg[tg] = acc[tg] + bout[tg];
    float m = lg[0];
#pragma unroll
    for (int tg = 1; tg < 9; tg++) m = fmaxf(m, lg[tg]);
    float ssum = 0.0f;
#pragma unroll
    for (int tg = 0; tg < 9; tg++) ssum += expf(lg[tg] - m);
    float lse = m + logf(ssum);
    float myo = lg[0] - lse;
#pragma unroll
    for (int tg = 1; tg < 9; tg++) if (L == tg) myo = lg[tg] - lse;
    if (L < 9) ws[EM_OFF + (size_t)wid * 9 + L] = myo;
}

// merged CRF: blocks 0..7 numerator, 8..15 forward(logZ), 16..23 viterbi
__global__ __launch_bounds__(512) void crf_all(
    const int* __restrict__ x, const int* __restrict__ bio,
    const float* __restrict__ start_t, const float* __restrict__ end_t,
    const float* __restrict__ trans, float* __restrict__ ws,
    float* __restrict__ out)
{
    const float* em = ws + EM_OFF;
    const int role  = blockIdx.x >> 3;
    const int local = blockIdx.x & 7;
    const int tid   = threadIdx.x;

    __shared__ float sc[9][8];
    __shared__ unsigned char hist[SS - 1][8][9];

    if (role == 0) {
        // ---- numerator: wave per b, lanes split s ----
        int b = local * 8 + (tid >> 6);
        int L = tid & 63;
        float sum = 0.0f;
        int cntm = 0;
#pragma unroll
        for (int j = 0; j < 8; j++) {
            int s = j * 64 + L;
            int tg = bio[s * BB + b];
            bool mk = (x[s * BB + b] != 0);
            cntm += mk ? 1 : 0;
            if (s == 0) {
                sum += start_t[tg] + em[(size_t)b * 9 + tg];
            } else if (mk) {
                int tp = bio[(s - 1) * BB + b];
                sum += em[((size_t)s * BB + b) * 9 + tg] + trans[tp * 9 + tg];
            }
        }
#pragma unroll
        for (int d = 1; d < 64; d <<= 1) {
            sum += __shfl_xor(sum, d, 64);
            cntm += __shfl_xor(cntm, d, 64);
        }
        if (L == 0) {
            int se = cntm - 1;
            sum += end_t[bio[se * BB + b]];
            ws[NUM_OFF + b] = sum;
        }
        return;
    }

    const int b_l = tid & 7;
    const int j   = tid >> 3;          // active j < 9
    const int b   = local * 8 + b_l;
    float tc[9];
    if (j < 9) {
#pragma unroll
        for (int i = 0; i < 9; i++) tc[i] = trans[i * 9 + j];
        sc[j][b_l] = start_t[j] + em[(size_t)b * 9 + j];
    }
    __syncthreads();

    if (role == 1) {
        // ---- forward logZ ----
        for (int s = 1; s < SS; s++) {
            float nv = 0.0f;
            if (j < 9) {
                float sv[9];
                float m = -3.4e38f;
#pragma unroll
                for (int i = 0; i < 9; i++) {
                    sv[i] = sc[i][b_l] + tc[i];
                    m = fmaxf(m, sv[i]);
                }
                float ssum = 0.0f;
#pragma unroll
                for (int i = 0; i < 9; i++) ssum += expf(sv[i] - m);
                nv = m + logf(ssum) + em[((size_t)s * BB + b) * 9 + j];
            }
            bool mk = (x[s * BB + b] != 0);
            __syncthreads();
            if (j < 9 && mk) sc[j][b_l] = nv;
            __syncthreads();
        }
        if (j == 0) {
            float m = -3.4e38f;
#pragma unroll
            for (int i = 0; i < 9; i++) m = fmaxf(m, sc[i][b_l] + end_t[i]);
            float ssum = 0.0f;
#pragma unroll
            for (int i = 0; i < 9; i++) ssum += expf(sc[i][b_l] + end_t[i] - m);
            ws[NORM_OFF + b] = m + logf(ssum);
        }
    } else {
        // ---- viterbi ----
        for (int s = 1; s < SS; s++) {
            float nv = 0.0f;
            if (j < 9) {
                float best = sc[0][b_l] + tc[0];
                int bi = 0;
#pragma unroll
                for (int i = 1; i < 9; i++) {
                    float v = sc[i][b_l] + tc[i];
                    if (v > best) { best = v; bi = i; }  // first-max = jnp.argmax
                }
                hist[s - 1][b_l][j] = (unsigned char)bi;
                nv = best + em[((size_t)s * BB + b) * 9 + j];
            }
            __syncthreads();
            if (j < 9) sc[j][b_l] = nv;
            __syncthreads();
        }
        if (tid < 8) {
            int bl = tid;
            int gb = local * 8 + bl;
            float best = sc[0][bl] + end_t[0];
            int cur = 0;
#pragma unroll
            for (int i = 1; i < 9; i++) {
                float v = sc[i][bl] + end_t[i];
                if (v > best) { best = v; cur = i; }
            }
            out[1 + (size_t)(SS - 1) * BB + gb] = (float)cur;
            for (int s = SS - 2; s >= 0; s--) {
                cur = hist[s][bl][cur];
                out[1 + (size_t)s * BB + gb] = (float)cur;
            }
        }
    }
}

__global__ __launch_bounds__(64) void final_llh(const float* __restrict__ ws,
                                               float* __restrict__ out)
{
    int L = threadIdx.x;
    float v = ws[NUM_OFF + L] - ws[NORM_OFF + L];
    v += __shfl_xor(v, 1, 64);
    v += __shfl_xor(v, 2, 64);
    v += __shfl_xor(v, 4, 64);
    v += __shfl_xor(v, 8, 64);
    v += __shfl_xor(v, 16, 64);
    v += __shfl_xor(v, 32, 64);
    if (L == 0) out[0] = -v;
}

extern "C" void kernel_launch(void* const* d_in, const int* in_sizes, int n_in,
                              void* d_out, int out_size, void* d_ws, size_t ws_size,
                              hipStream_t stream) {
    const int*   x       = (const int*)d_in[0];
    const int*   bio     = (const int*)d_in[1];
    const float* emb     = (const float*)d_in[2];
    const float* W_ih    = (const float*)d_in[3];
    const float* W_hh    = (const float*)d_in[4];
    const float* b_ih    = (const float*)d_in[5];
    const float* b_hh    = (const float*)d_in[6];
    const float* W_out   = (const float*)d_in[7];
    const float* b_out   = (const float*)d_in[8];
    const float* start_t = (const float*)d_in[9];
    const float* end_t   = (const float*)d_in[10];
    const float* trans   = (const float*)d_in[11];
    float* out = (float*)d_out;
    float* ws  = (float*)d_ws;

    init_barriers<<<512, 256, 0, stream>>>(ws);
    lstm_persistent<<<NWG, 512, 0, stream>>>(W_hh, W_ih, b_ih, b_hh, emb, x, ws);
    emis_kernel<<<SS * BB / 4, 256, 0, stream>>>(W_out, b_out, ws);
    crf_all<<<24, 512, 0, stream>>>(x, bio, start_t, end_t, trans, ws, out);
    final_llh<<<1, 64, 0, stream>>>(ws, out);
}

// Round 4
// 6099.474 us; speedup vs baseline: 7.7278x; 6.1930x over previous
//
#include <hip/hip_runtime.h>
#include <math.h>

#define SS 512
#define BB 64
#define EE 256
#define HH 512
#define NT 9
#define NWG 256
#define GBG 32   // workgroups per batch-group barrier

// ws layout (float32 elements):
//  hs   : SS*BB*HH at 0        (hs[t] = h_t)
//  em   : SS*BB*NT at EM_OFF
//  num  : 64 at NUM_OFF
//  norm : 64 at NORM_OFF
//  cnt  : SS*8*16 u32 at BAR_OFF          (64B-strided counters [t][bg])
//  flag : SS*8*16 u32 after cnt
#define HS_ELEMS ((size_t)SS * BB * HH)
#define EM_OFF   HS_ELEMS
#define NUM_OFF  (EM_OFF + (size_t)SS * BB * NT)
#define NORM_OFF (NUM_OFF + 64)
#define BAR_OFF  (NORM_OFF + 64)
#define BAR_U32S ((size_t)SS * 8 * 16)

// dynamic LDS layout (floats)
#define L_WHH 0            // 64 rows x 512       = 32768 floats (128 KB)
#define L_H   32768        // 8 x 520             = 4160
#define L_GSM 36928        // 64 x 9              = 576
#define L_CS  37504        // 16 x 8              = 128
#define L_TOT 37632        // 150528 bytes

__global__ __launch_bounds__(256) void init_barriers(float* __restrict__ ws) {
    unsigned* bar = (unsigned*)(ws + BAR_OFF);
    size_t idx = (size_t)blockIdx.x * 256 + threadIdx.x;
    if (idx < 2 * BAR_U32S) bar[idx] = 0u;
}

// Persistent LSTM: 256 WGs x 512 threads, one step per (per-bg) barrier round.
// WG (slice = wg&31, bg = wg>>5): units slice*16..+16, batches bg*8..+8.
// Wave w: local gate-rows w*8..w*8+7 (row l = gate*16 + unit_local).
// Lane L: b_l = L&7, kc = L>>3.
// Whh lives in LDS (staged once) -> zero per-step Whh memory traffic.
// Cross-WG data via RELAXED agent atomics (LLC-coherent, no invalidations).
__global__ __launch_bounds__(512) void lstm_persistent(
    const float* __restrict__ Whh, const float* __restrict__ Wih,
    const float* __restrict__ bih, const float* __restrict__ bhh,
    const float* __restrict__ emb, const int* __restrict__ x,
    float* __restrict__ ws)
{
    const int wg    = blockIdx.x;
    const int slice = wg & 31;
    const int bg    = wg >> 5;
    const int tid   = threadIdx.x;
    const int w     = tid >> 6;
    const int L     = tid & 63;
    const int b_l   = L & 7;
    const int kc    = L >> 3;
    const int b     = bg * 8 + b_l;

    float* hs = ws;
    unsigned* cnt  = (unsigned*)(ws + BAR_OFF);
    unsigned* flag = cnt + BAR_U32S;

    extern __shared__ float smem[];
    float* whh_l = smem + L_WHH;   // [l][512], l = local gate-row
    float* h_l   = smem + L_H;     // [b_l][520]
    float* gsm   = smem + L_GSM;   // [64][9]
    float* cs_l  = smem + L_CS;    // [u][8]

    int grow[8];
#pragma unroll
    for (int r = 0; r < 8; r++) {
        int l = w * 8 + r;
        grow[r] = (l >> 4) * HH + slice * 16 + (l & 15);
    }

    // ---- stage Whh slice (64 rows x 512) into LDS, coalesced ----
    for (int j = 0; j < 64; j++) {
        int idx = j * 512 + tid;          // l*512 + k
        int l = idx >> 9;
        int k = idx & 511;
        int gr = (l >> 4) * HH + slice * 16 + (l & 15);
        whh_l[idx] = Whh[(size_t)gr * HH + k];
    }

    // bias preload (activation threads only)
    float bs0 = 0.f, bs1 = 0.f, bs2 = 0.f, bs3 = 0.f;
    if (tid < 128) {
        const int u  = tid & 15;
        const int bb = tid >> 4;
        const int gu = slice * 16 + u;
        bs0 = bih[0 * HH + gu] + bhh[0 * HH + gu];
        bs1 = bih[1 * HH + gu] + bhh[1 * HH + gu];
        bs2 = bih[2 * HH + gu] + bhh[2 * HH + gu];
        bs3 = bih[3 * HH + gu] + bhh[3 * HH + gu];
        cs_l[u * 8 + bb] = 0.0f;
    }

    // h_{-1} = 0 locally
#pragma unroll
    for (int j = 0; j < 8; j++) {
        int idx = j * 512 + tid;
        h_l[(idx >> 9) * 520 + (idx & 511)] = 0.0f;
    }

    // ih-gates for t=0
    float acc_ih[8];
    {
        const int xv = x[0 * BB + b];
        const float* erow = emb + (size_t)xv * EE;
#pragma unroll
        for (int r = 0; r < 8; r++) acc_ih[r] = 0.0f;
        for (int c = 0; c < 8; c++) {
            const int k0 = c * 32 + kc * 4;
            float4 e4 = *(const float4*)(erow + k0);
            e4.x *= 16.0f; e4.y *= 16.0f; e4.z *= 16.0f; e4.w *= 16.0f;
#pragma unroll
            for (int r = 0; r < 8; r++) {
                float4 w4 = *(const float4*)(Wih + (size_t)grow[r] * EE + k0);
                acc_ih[r] += w4.x * e4.x + w4.y * e4.y + w4.z * e4.z + w4.w * e4.w;
            }
        }
    }
    __syncthreads();

    const float* wbase = whh_l + (size_t)(w * 8) * 512;

    for (int t = 0; t < SS; t++) {
        // ---- hh gates (Whh from LDS) ----
        float acc[8];
#pragma unroll
        for (int r = 0; r < 8; r++) acc[r] = acc_ih[r];
        const float* hrow = h_l + b_l * 520;
        for (int c = 0; c < 16; c++) {
            const int k0 = c * 32 + kc * 4;
            float4 h4 = *(const float4*)(hrow + k0);
#pragma unroll
            for (int r = 0; r < 8; r++) {
                float4 w4 = *(const float4*)(wbase + r * 512 + k0);
                acc[r] += w4.x * h4.x + w4.y * h4.y + w4.z * h4.z + w4.w * h4.w;
            }
        }

        // reduce over 8 kc-lanes
#pragma unroll
        for (int r = 0; r < 8; r++) {
            acc[r] += __shfl_xor(acc[r], 8, 64);
            acc[r] += __shfl_xor(acc[r], 16, 64);
            acc[r] += __shfl_xor(acc[r], 32, 64);
        }
        float myv = acc[0];
#pragma unroll
        for (int r = 1; r < 8; r++) if (kc == r) myv = acc[r];
        gsm[(w * 8 + kc) * 9 + b_l] = myv;
        __syncthreads();

        // ---- activations + state update + h_t store (relaxed agent) ----
        if (tid < 128) {
            const int u  = tid & 15;
            const int bb = tid >> 4;
            const int gu = slice * 16 + u;
            float gi = gsm[(0 * 16 + u) * 9 + bb] + bs0;
            float gf = gsm[(1 * 16 + u) * 9 + bb] + bs1;
            float gg = gsm[(2 * 16 + u) * 9 + bb] + bs2;
            float go = gsm[(3 * 16 + u) * 9 + bb] + bs3;
            float i_ = 1.0f / (1.0f + expf(-gi));
            float f_ = 1.0f / (1.0f + expf(-gf));
            float o_ = 1.0f / (1.0f + expf(-go));
            const int gb = bg * 8 + bb;
            float cn = f_ * cs_l[u * 8 + bb] + i_ * tanhf(gg);
            float hn = o_ * tanhf(cn);
            cs_l[u * 8 + bb] = cn;
            __hip_atomic_store(&hs[(size_t)t * BB * HH + (size_t)gb * HH + gu],
                               hn, __ATOMIC_RELAXED, __HIP_MEMORY_SCOPE_AGENT);
        }
        __syncthreads();   // vmcnt(0) before s_barrier: h stores at LLC

        // ---- arrive at per-bg barrier t ----
        if (tid == 0) {
            unsigned old = __hip_atomic_fetch_add(&cnt[((size_t)t * 8 + bg) * 16], 1u,
                                                  __ATOMIC_RELAXED,
                                                  __HIP_MEMORY_SCOPE_AGENT);
            if (old == GBG - 1)
                __hip_atomic_store(&flag[((size_t)t * 8 + bg) * 16], 1u,
                                   __ATOMIC_RELAXED, __HIP_MEMORY_SCOPE_AGENT);
        }

        if (t + 1 < SS) {
            // ---- ih(t+1) overlapped with the wait window ----
            {
                const int xv = x[(t + 1) * BB + b];
                const float* erow = emb + (size_t)xv * EE;
#pragma unroll
                for (int r = 0; r < 8; r++) acc_ih[r] = 0.0f;
                for (int c = 0; c < 8; c++) {
                    const int k0 = c * 32 + kc * 4;
                    float4 e4 = *(const float4*)(erow + k0);
                    e4.x *= 16.0f; e4.y *= 16.0f; e4.z *= 16.0f; e4.w *= 16.0f;
#pragma unroll
                    for (int r = 0; r < 8; r++) {
                        float4 w4 = *(const float4*)(Wih + (size_t)grow[r] * EE + k0);
                        acc_ih[r] += w4.x * e4.x + w4.y * e4.y + w4.z * e4.z + w4.w * e4.w;
                    }
                }
            }
            if (tid == 0) {
                while (__hip_atomic_load(&flag[((size_t)t * 8 + bg) * 16],
                                         __ATOMIC_RELAXED,
                                         __HIP_MEMORY_SCOPE_AGENT) == 0u) {}
            }
            __syncthreads();

            // ---- stage h_t into LDS (relaxed agent loads from LLC) ----
            const float* hsrc = hs + (size_t)t * BB * HH + (size_t)bg * 8 * HH;
#pragma unroll
            for (int j = 0; j < 8; j++) {
                int idx = j * 512 + tid;
                float v = __hip_atomic_load(&hsrc[idx], __ATOMIC_RELAXED,
                                            __HIP_MEMORY_SCOPE_AGENT);
                h_l[(idx >> 9) * 520 + (idx & 511)] = v;
            }
            __syncthreads();
        }
    }
}

// one wave per (t,b): logits = h @ W_out^T + b_out, then log_softmax
__global__ __launch_bounds__(256) void emis_kernel(
    const float* __restrict__ Wout, const float* __restrict__ bout,
    float* __restrict__ ws)
{
    int wid = blockIdx.x * 4 + (threadIdx.x >> 6);  // t*64 + b
    int L   = threadIdx.x & 63;
    const float* h = ws + (size_t)wid * HH;
    float hv[8];
#pragma unroll
    for (int i = 0; i < 8; i++) hv[i] = h[i * 64 + L];
    float acc[9];
#pragma unroll
    for (int tg = 0; tg < 9; tg++) acc[tg] = 0.0f;
    for (int i = 0; i < 8; i++) {
#pragma unroll
        for (int tg = 0; tg < 9; tg++)
            acc[tg] += Wout[tg * HH + i * 64 + L] * hv[i];
    }
#pragma unroll
    for (int tg = 0; tg < 9; tg++) {
        acc[tg] += __shfl_xor(acc[tg], 1, 64);
        acc[tg] += __shfl_xor(acc[tg], 2, 64);
        acc[tg] += __shfl_xor(acc[tg], 4, 64);
        acc[tg] += __shfl_xor(acc[tg], 8, 64);
        acc[tg] += __shfl_xor(acc[tg], 16, 64);
        acc[tg] += __shfl_xor(acc[tg], 32, 64);
    }
    float lg[9];
#pragma unroll
    for (int tg = 0; tg < 9; tg++) lg[tg] = acc[tg] + bout[tg];
    float m = lg[0];
#pragma unroll
    for (int tg = 1; tg < 9; tg++) m = fmaxf(m, lg[tg]);
    float ssum = 0.0f;
#pragma unroll
    for (int tg = 0; tg < 9; tg++) ssum += expf(lg[tg] - m);
    float lse = m + logf(ssum);
    float myo = lg[0] - lse;
#pragma unroll
    for (int tg = 1; tg < 9; tg++) if (L == tg) myo = lg[tg] - lse;
    if (L < 9) ws[EM_OFF + (size_t)wid * 9 + L] = myo;
}

// merged CRF: blocks 0..7 numerator, 8..15 forward(logZ), 16..23 viterbi
__global__ __launch_bounds__(512) void crf_all(
    const int* __restrict__ x, const int* __restrict__ bio,
    const float* __restrict__ start_t, const float* __restrict__ end_t,
    const float* __restrict__ trans, float* __restrict__ ws,
    float* __restrict__ out)
{
    const float* em = ws + EM_OFF;
    const int role  = blockIdx.x >> 3;
    const int local = blockIdx.x & 7;
    const int tid   = threadIdx.x;

    __shared__ float sc[9][8];
    __shared__ unsigned char hist[SS - 1][8][9];

    if (role == 0) {
        int b = local * 8 + (tid >> 6);
        int L = tid & 63;
        float sum = 0.0f;
        int cntm = 0;
#pragma unroll
        for (int j = 0; j < 8; j++) {
            int s = j * 64 + L;
            int tg = bio[s * BB + b];
            bool mk = (x[s * BB + b] != 0);
            cntm += mk ? 1 : 0;
            if (s == 0) {
                sum += start_t[tg] + em[(size_t)b * 9 + tg];
            } else if (mk) {
                int tp = bio[(s - 1) * BB + b];
                sum += em[((size_t)s * BB + b) * 9 + tg] + trans[tp * 9 + tg];
            }
        }
#pragma unroll
        for (int d = 1; d < 64; d <<= 1) {
            sum += __shfl_xor(sum, d, 64);
            cntm += __shfl_xor(cntm, d, 64);
        }
        if (L == 0) {
            int se = cntm - 1;
            sum += end_t[bio[se * BB + b]];
            ws[NUM_OFF + b] = sum;
        }
        return;
    }

    const int b_l = tid & 7;
    const int j   = tid >> 3;          // active j < 9
    const int b   = local * 8 + b_l;
    float tc[9];
    if (j < 9) {
#pragma unroll
        for (int i = 0; i < 9; i++) tc[i] = trans[i * 9 + j];
        sc[j][b_l] = start_t[j] + em[(size_t)b * 9 + j];
    }
    __syncthreads();

    if (role == 1) {
        for (int s = 1; s < SS; s++) {
            float nv = 0.0f;
            if (j < 9) {
                float sv[9];
                float m = -3.4e38f;
#pragma unroll
                for (int i = 0; i < 9; i++) {
                    sv[i] = sc[i][b_l] + tc[i];
                    m = fmaxf(m, sv[i]);
                }
                float ssum = 0.0f;
#pragma unroll
                for (int i = 0; i < 9; i++) ssum += expf(sv[i] - m);
                nv = m + logf(ssum) + em[((size_t)s * BB + b) * 9 + j];
            }
            bool mk = (x[s * BB + b] != 0);
            __syncthreads();
            if (j < 9 && mk) sc[j][b_l] = nv;
            __syncthreads();
        }
        if (j == 0) {
            float m = -3.4e38f;
#pragma unroll
            for (int i = 0; i < 9; i++) m = fmaxf(m, sc[i][b_l] + end_t[i]);
            float ssum = 0.0f;
#pragma unroll
            for (int i = 0; i < 9; i++) ssum += expf(sc[i][b_l] + end_t[i] - m);
            ws[NORM_OFF + b] = m + logf(ssum);
        }
    } else {
        for (int s = 1; s < SS; s++) {
            float nv = 0.0f;
            if (j < 9) {
                float best = sc[0][b_l] + tc[0];
                int bi = 0;
#pragma unroll
                for (int i = 1; i < 9; i++) {
                    float v = sc[i][b_l] + tc[i];
                    if (v > best) { best = v; bi = i; }  // first-max = jnp.argmax
                }
                hist[s - 1][b_l][j] = (unsigned char)bi;
                nv = best + em[((size_t)s * BB + b) * 9 + j];
            }
            __syncthreads();
            if (j < 9) sc[j][b_l] = nv;
            __syncthreads();
        }
        if (tid < 8) {
            int bl = tid;
            int gb = local * 8 + bl;
            float best = sc[0][bl] + end_t[0];
            int cur = 0;
#pragma unroll
            for (int i = 1; i < 9; i++) {
                float v = sc[i][bl] + end_t[i];
                if (v > best) { best = v; cur = i; }
            }
            out[1 + (size_t)(SS - 1) * BB + gb] = (float)cur;
            for (int s = SS - 2; s >= 0; s--) {
                cur = hist[s][bl][cur];
                out[1 + (size_t)s * BB + gb] = (float)cur;
            }
        }
    }
}

__global__ __launch_bounds__(64) void final_llh(const float* __restrict__ ws,
                                               float* __restrict__ out)
{
    int L = threadIdx.x;
    float v = ws[NUM_OFF + L] - ws[NORM_OFF + L];
    v += __shfl_xor(v, 1, 64);
    v += __shfl_xor(v, 2, 64);
    v += __shfl_xor(v, 4, 64);
    v += __shfl_xor(v, 8, 64);
    v += __shfl_xor(v, 16, 64);
    v += __shfl_xor(v, 32, 64);
    if (L == 0) out[0] = -v;
}

extern "C" void kernel_launch(void* const* d_in, const int* in_sizes, int n_in,
                              void* d_out, int out_size, void* d_ws, size_t ws_size,
                              hipStream_t stream) {
    const int*   x       = (const int*)d_in[0];
    const int*   bio     = (const int*)d_in[1];
    const float* emb     = (const float*)d_in[2];
    const float* W_ih    = (const float*)d_in[3];
    const float* W_hh    = (const float*)d_in[4];
    const float* b_ih    = (const float*)d_in[5];
    const float* b_hh    = (const float*)d_in[6];
    const float* W_out   = (const float*)d_in[7];
    const float* b_out   = (const float*)d_in[8];
    const float* start_t = (const float*)d_in[9];
    const float* end_t   = (const float*)d_in[10];
    const float* trans   = (const float*)d_in[11];
    float* out = (float*)d_out;
    float* ws  = (float*)d_ws;

    const size_t dyn_lds = (size_t)L_TOT * sizeof(float);   // 150528 B
    static bool attr_set = false;
    if (!attr_set) {
        hipFuncSetAttribute((const void*)lstm_persistent,
                            hipFuncAttributeMaxDynamicSharedMemorySize,
                            (int)dyn_lds);
        attr_set = true;
    }

    init_barriers<<<512, 256, 0, stream>>>(ws);
    lstm_persistent<<<NWG, 512, dyn_lds, stream>>>(W_hh, W_ih, b_ih, b_hh, emb, x, ws);
    emis_kernel<<<SS * BB / 4, 256, 0, stream>>>(W_out, b_out, ws);
    crf_all<<<24, 512, 0, stream>>>(x, bio, start_t, end_t, trans, ws, out);
    final_llh<<<1, 64, 0, stream>>>(ws, out);
}